// Round 14
// baseline (416.021 us; speedup 1.0000x reference)
//
#include <hip/hip_runtime.h>

typedef _Float16 f16;
typedef _Float16 f16x8 __attribute__((ext_vector_type(8)));
typedef _Float16 f16x4 __attribute__((ext_vector_type(4)));
typedef float    f32x4 __attribute__((ext_vector_type(4)));
typedef unsigned int u32;
typedef u32 u32x2 __attribute__((ext_vector_type(2)));
typedef u32 u32x4 __attribute__((ext_vector_type(4)));
typedef unsigned short ush;

#define CC 256
#define NN 4096
#define BB 4
#define RSC 17          // combine buffer stride (f32)

union Frag8 { u32x4 u4; f16x8 f; };
union Frag4 { u32x2 u2; f16x4 f; };

static __device__ __forceinline__ u32 pkrtz(float a, float b) {
  auto t = __builtin_amdgcn_cvt_pkrtz(a, b);
  return __builtin_bit_cast(u32, t);
}
static __device__ __forceinline__ ush f2h(float x) {   // RNE
  f16 h = (f16)x;
  return __builtin_bit_cast(ush, h);
}

static __device__ __forceinline__ void gload16(const ush* g, ush* l) {
  __builtin_amdgcn_global_load_lds(
      (const __attribute__((address_space(1))) u32*)g,
      (__attribute__((address_space(3))) u32*)l, 16, 0, 0);
}

#define MFMA32(A, B, C) __builtin_amdgcn_mfma_f32_16x16x32_f16((A), (B), (C), 0, 0, 0)
#define MFMA16(A, B, C) __builtin_amdgcn_mfma_f32_16x16x16f16((A), (B), (C), 0, 0, 0)

// K1: M[c][cp] = sum_o w1[o,c]*w2[o,cp] ; g[cp] = sum_o b1[o]*w2[o,cp]
__global__ void k_prep(const float* __restrict__ w1, const float* __restrict__ w2,
                       const float* __restrict__ b1, float* __restrict__ M,
                       float* __restrict__ g) {
  const int c  = blockIdx.x;
  const int cp = threadIdx.x;
  float acc = 0.f;
#pragma unroll 8
  for (int o = 0; o < CC; ++o)
    acc += w1[o * CC + c] * w2[o * CC + cp];
  M[c * CC + cp] = acc;
  if (c == 0) {
    float ga = 0.f;
    for (int o = 0; o < CC; ++o)
      ga += b1[o] * w2[o * CC + cp];
    g[cp] = ga;
  }
}

// K-cvt: x2 tile -> kimg (swizzled [j][c] LDS byte-image) + vimg (PV-fragment
// order) + r2[b,j] = sum_c g[c]*x2[b,c,j].   (all fp16 RNE)
// K image row j (512B): 16B slot st holds halves c=8s..8s+7 with s = st^(j&7).
__global__ void k_cvt(const float* __restrict__ x2, const float* __restrict__ g,
                      ush* __restrict__ kimg, ush* __restrict__ vimg,
                      float* __restrict__ r2) {
  __shared__ float Xs[256 * 37];
  __shared__ float Ps[32 * 9];
  const int tid = threadIdx.x;
  const int b   = blockIdx.x >> 7;
  const int jt  = blockIdx.x & 127;
  const int j0  = jt << 5;
  const float* x2b = x2 + ((size_t)b << 20);
  {
    const int jf = tid & 7, c0 = tid >> 3;
#pragma unroll
    for (int m = 0; m < 8; ++m) {
      int c = c0 + (m << 5);
      float4 v = *(const float4*)(x2b + ((size_t)c << 12) + j0 + (jf << 2));
      *(float4*)(Xs + c * 37 + (jf << 2)) = v;
    }
  }
  __syncthreads();
  const size_t tile = ((size_t)blockIdx.x) << 13;   // halves
  {
    ush* kp = kimg + tile;
#pragma unroll
    for (int m = 0; m < 4; ++m) {
      int idx = tid + (m << 8);
      int j = idx >> 5, st = idx & 31;
      int s = st ^ (j & 7);
      u32 hw[4];
#pragma unroll
      for (int k = 0; k < 4; ++k) {
        float a  = Xs[(8 * s + 2 * k) * 37 + j];
        float c2 = Xs[(8 * s + 2 * k + 1) * 37 + j];
        hw[k] = (u32)f2h(a) | ((u32)f2h(c2) << 16);
      }
      u32x4 v; v.x = hw[0]; v.y = hw[1]; v.z = hw[2]; v.w = hw[3];
      *(u32x4*)(kp + (idx << 3)) = v;
    }
  }
  {
    ush* vp = vimg + tile;
#pragma unroll
    for (int mm = 0; mm < 4; ++mm) {
      int e = tid + (mm << 8);
      int lqe = e & 15, ge = (e >> 4) & 3, he = (e >> 6) & 1, me = e >> 7;
      int c0 = lqe + (me << 5);
      int q0 = (he << 4) + (ge << 2);
      const float* r0 = Xs + c0 * 37 + q0;
      const float* r1 = Xs + (c0 + 16) * 37 + q0;
      u32x4 v;
      v.x = (u32)f2h(r0[0]) | ((u32)f2h(r0[1]) << 16);
      v.y = (u32)f2h(r0[2]) | ((u32)f2h(r0[3]) << 16);
      v.z = (u32)f2h(r1[0]) | ((u32)f2h(r1[1]) << 16);
      v.w = (u32)f2h(r1[2]) | ((u32)f2h(r1[3]) << 16);
      *(u32x4*)(vp + (e << 3)) = v;
    }
  }
  {
    const int j = tid & 31, s = tid >> 5;
    float acc = 0.f;
#pragma unroll 8
    for (int k = 0; k < 32; ++k)
      acc += g[(s << 5) + k] * Xs[((s << 5) + k) * 37 + j];
    Ps[j * 9 + s] = acc;
  }
  __syncthreads();
  if (tid < 32) {
    float a = 0.f;
#pragma unroll
    for (int s = 0; s < 8; ++s) a += Ps[tid * 9 + s];
    r2[(b << 12) + j0 + tid] = a;
  }
}

// K3: QT=32, 512 threads, 8 waves = (p:2 i) x (q:2 c) x (h:2 j).
// Producer/consumer (r13) + DEPTH-2 pipeline: K tri-buffered LDS (issue t+2
// at tile top), V/r2 triple register sets (issue t+2 after PV). One counted
// vmcnt per tile (producer 7 / consumer 6); cover ~2 tiles of L3 latency.
__launch_bounds__(512, 4)
__global__ void k_attn(const float* __restrict__ x1, const ush* __restrict__ kimg,
                       const ush* __restrict__ vimg, const float* __restrict__ M,
                       const float* __restrict__ r2, float* __restrict__ out) {
  extern __shared__ ush lds[];
  const int tid  = threadIdx.x;
  const int lane = tid & 63;
  const int w    = tid >> 6;
  const int h    = w & 1;          // j-group
  const int q    = (w >> 1) & 1;   // c-group (0 = producer)
  const int p    = w >> 2;         // i-group
  const int g    = lane >> 4;
  const int lq   = lane & 15;
  const int phb  = ((p << 1) + h) << 6;

  int bid = (int)blockIdx.x;
  bid = (bid & 7) * 64 + (bid >> 3);        // bijective XCD swizzle (512 = 8*64)
  const int b  = bid >> 7;
  const int i0 = (bid & 127) << 5;

  const float* x1b = x1 + ((size_t)b << 20);

  // ---- Q-prep (VALU f32, two 16-i passes); x1f @0 (18KB), Qhi @ byte 18432 ----
  float* x1f = (float*)lds;                 // [256][18] f32
  ush* Qhi = lds + 9216;                    // [32][256] halves
  for (int ih = 0; ih < 2; ++ih) {
    {
      const int jf = tid & 3, c0 = tid >> 2;
#pragma unroll
      for (int m = 0; m < 2; ++m) {
        int c = c0 + (m << 7);
        float4 v = *(const float4*)(x1b + ((size_t)c << 12) + i0 + (ih << 4) + (jf << 2));
        *(float4*)(x1f + c * 18 + (jf << 2)) = v;
      }
    }
    __syncthreads();
    {
      const int tc = tid & 63, iq = tid >> 6;   // i = 16ih + 2iq + e
      float acc[4][2];
#pragma unroll
      for (int a = 0; a < 4; ++a) { acc[a][0] = 0.f; acc[a][1] = 0.f; }
#pragma unroll 4
      for (int c = 0; c < CC; ++c) {
        float4 mv = *(const float4*)(M + c * CC + (tc << 2));
        float x0  = x1f[c * 18 + (iq << 1)];
        float x1v = x1f[c * 18 + (iq << 1) + 1];
        acc[0][0] += mv.x * x0; acc[0][1] += mv.x * x1v;
        acc[1][0] += mv.y * x0; acc[1][1] += mv.y * x1v;
        acc[2][0] += mv.z * x0; acc[2][1] += mv.z * x1v;
        acc[3][0] += mv.w * x0; acc[3][1] += mv.w * x1v;
      }
#pragma unroll
      for (int e = 0; e < 2; ++e) {
        int i = (ih << 4) + (iq << 1) + e;
        u32 h0 = (u32)f2h(acc[0][e]) | ((u32)f2h(acc[1][e]) << 16);
        u32 h1 = (u32)f2h(acc[2][e]) | ((u32)f2h(acc[3][e]) << 16);
        u32x2 hw; hw.x = h0; hw.y = h1;
        *(u32x2*)(Qhi + (i << 8) + (tc << 2)) = hw;
      }
    }
    __syncthreads();
  }

  // ---- preload Q fragments (producers only) ----
  Frag8 QBh[8];
  if (q == 0) {
    const int qoff = ((p << 4) + lq) << 8;
#pragma unroll
    for (int cs = 0; cs < 8; ++cs)
      QBh[cs].u4 = *(const u32x4*)(Qhi + qoff + (cs << 5) + (g << 3));
  }
  __syncthreads();

  // ---- main flash loop ----
  f32x4 vacc[8];
#pragma unroll
  for (int n = 0; n < 8; ++n) vacc[n] = (f32x4){0.f, 0.f, 0.f, 0.f};
  float m_run = -3.0e38f, l_run = 0.f;

  const int sx   = lq & 7;
  const int koff = ((h << 4) + lq) << 8;    // K row (halves)
  const float* r2p = r2 + (b << 12) + (h << 4) + (g << 2);
  const size_t bt = (size_t)(b << 7);
  const ush* vbase = vimg + (bt << 13) + (q << 12) + (h << 9) + (g << 7) + (lq << 3);

  u32x2* Pb  = (u32x2*)(lds + 24576);       // byte 49152: [4 ph][64 lane] x 8B
  float* Scf = (float*)(lds + 25600);       // byte 51200: [4 ph][64 lane] x 4B

  Frag8 VdA[4], VdB[4], VdC[4];
  float4 r2a, r2b, r2c_;

  // prologue: issue tiles 0 and 1 (K->buf0/buf1, V->VdA/VdB, r2->a/b)
  {
    const ush* gk0 = kimg + (bt << 13);
    gload16(gk0 + ((size_t)tid << 3),         lds + (tid << 3));
    gload16(gk0 + ((size_t)(tid + 512) << 3), lds + ((tid + 512) << 3));
#pragma unroll
    for (int m = 0; m < 4; ++m)
      VdA[m].u4 = *(const u32x4*)(vbase + (m << 10));
    if (q == 0) r2a = *(const float4*)(r2p);
    const ush* gk1 = kimg + ((bt + 1) << 13);
    gload16(gk1 + ((size_t)tid << 3),         lds + 8192 + (tid << 3));
    gload16(gk1 + ((size_t)(tid + 512) << 3), lds + 8192 + ((tid + 512) << 3));
#pragma unroll
    for (int m = 0; m < 4; ++m)
      VdB[m].u4 = *(const u32x4*)(vbase + 8192 + (m << 10));
    if (q == 0) r2b = *(const float4*)(r2p + 32);
  }
  __builtin_amdgcn_sched_barrier(0);
  if (q == 0) asm volatile("s_waitcnt vmcnt(7)" ::: "memory");
  else        asm volatile("s_waitcnt vmcnt(6)" ::: "memory");
  __builtin_amdgcn_sched_barrier(0);
  __builtin_amdgcn_s_barrier();

  auto body = [&](int t, Frag8 (&Vc)[4], Frag8 (&Vt)[4],
                  float4& r2cur, float4& r2tgt, int rdo) {
    // top: issue K(t+2) into buffer (t+2)%3
    if (t + 2 < 128) {
      int wr = rdo + 16384; if (wr >= 24576) wr -= 24576;
      const ush* gk = kimg + ((bt + t + 2) << 13);
      gload16(gk + ((size_t)tid << 3),         lds + wr + (tid << 3));
      gload16(gk + ((size_t)(tid + 512) << 3), lds + wr + ((tid + 512) << 3));
    }
    __builtin_amdgcn_sched_barrier(0);

    float scl;
    Frag4 Pf;
    if (q == 0) {
      // producer: S = K·Q once, softmax, publish P + scl
      const ush* kb = lds + rdo;
      f32x4 a1 = {0.f,0.f,0.f,0.f}, a2 = {0.f,0.f,0.f,0.f};
#pragma unroll
      for (int cs = 0; cs < 8; cs += 2) {
        int st1 = ((cs << 2) + g) ^ sx;
        int st2 = (((cs + 1) << 2) + g) ^ sx;
        Frag8 A1; A1.u4 = *(const u32x4*)(kb + koff + (st1 << 3));
        Frag8 A2; A2.u4 = *(const u32x4*)(kb + koff + (st2 << 3));
        a1 = MFMA32(A1.f, QBh[cs].f, a1);
        a2 = MFMA32(A2.f, QBh[cs + 1].f, a2);
      }
      float s0 = a1[0] + a2[0] + r2cur.x, s1 = a1[1] + a2[1] + r2cur.y;
      float s2 = a1[2] + a2[2] + r2cur.z, s3 = a1[3] + a2[3] + r2cur.w;
      float mx = fmaxf(fmaxf(s0, s1), fmaxf(s2, s3));
      mx = fmaxf(mx, __shfl_xor(mx, 16));
      mx = fmaxf(mx, __shfl_xor(mx, 32));
      float mn = fmaxf(m_run, mx);
      scl = __expf(m_run - mn);
      float p0 = __expf(s0 - mn), p1 = __expf(s1 - mn);
      float p2 = __expf(s2 - mn), p3 = __expf(s3 - mn);
      float rs = p0 + p1 + p2 + p3;
      rs += __shfl_xor(rs, 16);
      rs += __shfl_xor(rs, 32);
      l_run = l_run * scl + rs;
      m_run = mn;
      Pf.u2.x = pkrtz(p0, p1);
      Pf.u2.y = pkrtz(p2, p3);
      Pb[phb + lane] = Pf.u2;
      Scf[phb + lane] = scl;
      asm volatile("s_waitcnt lgkmcnt(0)" ::: "memory");
    }
    __builtin_amdgcn_sched_barrier(0);
    __builtin_amdgcn_s_barrier();          // P + scl visible

    if (q == 1) {
      Pf.u2 = Pb[phb + lane];
      scl   = Scf[phb + lane];
    }

    if (!__all(scl == 1.0f)) {
#pragma unroll
      for (int n = 0; n < 8; ++n) {
        vacc[n][0] *= scl; vacc[n][1] *= scl;
        vacc[n][2] *= scl; vacc[n][3] *= scl;
      }
    }
#pragma unroll
    for (int m = 0; m < 4; ++m) {
      Frag4 Va, Vb;
      Va.u2.x = Vc[m].u4.x; Va.u2.y = Vc[m].u4.y;     // n = 2m
      Vb.u2.x = Vc[m].u4.z; Vb.u2.y = Vc[m].u4.w;     // n = 2m+1
      vacc[2 * m]     = MFMA16(Va.f, Pf.f, vacc[2 * m]);
      vacc[2 * m + 1] = MFMA16(Vb.f, Pf.f, vacc[2 * m + 1]);
    }

    // end: issue V(t+2)+r2(t+2); single counted wait for tile t+1's ops
    if (t + 2 < 128) {
      const ush* vt_ = vbase + ((size_t)(t + 2) << 13);
#pragma unroll
      for (int m = 0; m < 4; ++m)
        Vt[m].u4 = *(const u32x4*)(vt_ + (m << 10));
      if (q == 0) r2tgt = *(const float4*)(r2p + ((t + 2) << 5));
      __builtin_amdgcn_sched_barrier(0);
      if (q == 0) asm volatile("s_waitcnt vmcnt(7)" ::: "memory");
      else        asm volatile("s_waitcnt vmcnt(6)" ::: "memory");
    } else {
      asm volatile("s_waitcnt vmcnt(0)" ::: "memory");
    }
    __builtin_amdgcn_sched_barrier(0);
    __builtin_amdgcn_s_barrier();          // K(t+1) buffer ready, P consumed
  };

  for (int tt = 0; tt < 126; tt += 3) {
    body(tt,     VdA, VdC, r2a,  r2c_, 0);
    body(tt + 1, VdB, VdA, r2b,  r2a,  8192);
    body(tt + 2, VdC, VdB, r2c_, r2b,  16384);
  }
  body(126, VdA, VdC, r2a, r2c_, 0);
  body(127, VdB, VdA, r2b, r2a,  8192);

  // ---- merge j-halves, normalize, store ----
  __syncthreads();
  float* Cmb = (float*)lds;                 // [2 p][256 c][17] f32 = 34816B
  float* Msm = (float*)(lds + 17408);       // byte 34816
  float* Lsm = Msm + 64;
  if (q == 0 && g == 0) {
    Msm[p * 32 + h * 16 + lq] = m_run;
    Lsm[p * 32 + h * 16 + lq] = l_run;
  }
  __syncthreads();
  float m_own = (q == 0) ? m_run : Msm[p * 32 + h * 16 + lq];
  float l_own = (q == 0) ? l_run : Lsm[p * 32 + h * 16 + lq];
  float mo  = Msm[p * 32 + (1 - h) * 16 + lq];
  float lo2 = Lsm[p * 32 + (1 - h) * 16 + lq];
  float mt    = fmaxf(m_own, mo);
  float aSelf = __expf(m_own - mt);
  float l_tot = l_own * aSelf + lo2 * __expf(mo - mt);

  if (h == 0) {
    float* cb_ = Cmb + p * (CC * RSC);
#pragma unroll
    for (int n = 0; n < 8; ++n)
#pragma unroll
      for (int r = 0; r < 4; ++r) {
        int c = (q << 7) + (n << 4) + (g << 2) + r;
        cb_[c * RSC + lq] = vacc[n][r] * aSelf;
      }
  }
  __syncthreads();
  if (h == 1) {
    const float* cb_ = Cmb + p * (CC * RSC);
    float inv = 1.f / l_tot;
    float* ob = out + ((size_t)b << 20) + i0 + (p << 4) + lq;
#pragma unroll
    for (int n = 0; n < 8; ++n)
#pragma unroll
      for (int r = 0; r < 4; ++r) {
        int c = (q << 7) + (n << 4) + (g << 2) + r;
        ob[(size_t)c << 12] = (vacc[n][r] * aSelf + cb_[c * RSC + lq]) * inv;
      }
  }
}

extern "C" void kernel_launch(void* const* d_in, const int* in_sizes, int n_in,
                              void* d_out, int out_size, void* d_ws, size_t ws_size,
                              hipStream_t stream) {
  const float* x1 = (const float*)d_in[0];
  const float* x2 = (const float*)d_in[1];
  const float* w1 = (const float*)d_in[2];
  const float* b1 = (const float*)d_in[3];
  const float* w2 = (const float*)d_in[4];
  // b2 (d_in[5]) contributes only row-constant energy terms -> cancels in softmax.

  float* M  = (float*)d_ws;            // 256KB
  float* g  = M + 65536;
  float* r2 = g + 256;                 // 64KB
  ush* kimg = (ush*)(r2 + 16384);      // 8MB, per-tile 16KB LDS byte-images
  ush* vimg = kimg + 4194304;          // 8MB, per-tile PV-fragment-ordered fp16
  float* outp = (float*)d_out;

  const int LDS_BYTES = 52224;
  (void)hipFuncSetAttribute((const void*)k_attn,
                            hipFuncAttributeMaxDynamicSharedMemorySize, LDS_BYTES);

  k_prep<<<CC, 256, 0, stream>>>(w1, w2, b1, M, g);
  k_cvt<<<BB * (NN / 32), 256, 0, stream>>>(x2, g, kimg, vimg, r2);
  k_attn<<<BB * (NN / 32), 512, LDS_BYTES, stream>>>(x1, kimg, vimg, M, r2, outp);
  (void)in_sizes; (void)n_in; (void)out_size; (void)ws_size;
}

// Round 15
// 370.020 us; speedup vs baseline: 1.1243x; 1.1243x over previous
//
#include <hip/hip_runtime.h>

typedef _Float16 f16;
typedef _Float16 f16x8 __attribute__((ext_vector_type(8)));
typedef float    f32x4 __attribute__((ext_vector_type(4)));
typedef unsigned int u32;
typedef u32 u32x2 __attribute__((ext_vector_type(2)));
typedef u32 u32x4 __attribute__((ext_vector_type(4)));
typedef unsigned short ush;

#define CC 256
#define NN 4096
#define BB 4
#define RSC 17          // combine buffer stride (f32)

union Frag8 { u32x4 u4; f16x8 f; };

static __device__ __forceinline__ u32 pkrtz(float a, float b) {
  auto t = __builtin_amdgcn_cvt_pkrtz(a, b);
  return __builtin_bit_cast(u32, t);
}
static __device__ __forceinline__ ush f2h(float x) {   // RNE
  f16 h = (f16)x;
  return __builtin_bit_cast(ush, h);
}
static __device__ __forceinline__ u32 pk2h(float a, float b) {
  return (u32)f2h(a) | ((u32)f2h(b) << 16);
}

static __device__ __forceinline__ void gload16(const ush* g, ush* l) {
  __builtin_amdgcn_global_load_lds(
      (const __attribute__((address_space(1))) u32*)g,
      (__attribute__((address_space(3))) u32*)l, 16, 0, 0);
}

#define MFMA32(A, B, C) __builtin_amdgcn_mfma_f32_16x16x32_f16((A), (B), (C), 0, 0, 0)

// K1: M[c][cp] = sum_o w1[o,c]*w2[o,cp] ; g[cp] = sum_o b1[o]*w2[o,cp]
__global__ void k_prep(const float* __restrict__ w1, const float* __restrict__ w2,
                       const float* __restrict__ b1, float* __restrict__ M,
                       float* __restrict__ g) {
  const int c  = blockIdx.x;
  const int cp = threadIdx.x;
  float acc = 0.f;
#pragma unroll 8
  for (int o = 0; o < CC; ++o)
    acc += w1[o * CC + c] * w2[o * CC + cp];
  M[c * CC + cp] = acc;
  if (c == 0) {
    float ga = 0.f;
    for (int o = 0; o < CC; ++o)
      ga += b1[o] * w2[o * CC + cp];
    g[cp] = ga;
  }
}

// K-cvt: x2 32-j chunk -> kimg (64j tiles: row j 512B, 16B slot st holds
// halves c=8s..8s+7, s = st^(j&7)) + vimg (64j tiles, PV A-fragment order:
// entry(q,n,sub,g,lq) 16B = V[c=(q<<7)+(n<<4)+lq][j0+8g..+7]) + r2.
__global__ void k_cvt(const float* __restrict__ x2, const float* __restrict__ g,
                      ush* __restrict__ kimg, ush* __restrict__ vimg,
                      float* __restrict__ r2) {
  __shared__ float Xs[256 * 37];
  __shared__ float Ps[32 * 9];
  const int tid = threadIdx.x;
  const int b   = blockIdx.x >> 7;
  const int jt  = blockIdx.x & 127;
  const int j0  = jt << 5;
  const int sub = jt & 1;
  const float* x2b = x2 + ((size_t)b << 20);
  {
    const int jf = tid & 7, c0 = tid >> 3;
#pragma unroll
    for (int m = 0; m < 8; ++m) {
      int c = c0 + (m << 5);
      float4 v = *(const float4*)(x2b + ((size_t)c << 12) + j0 + (jf << 2));
      *(float4*)(Xs + c * 37 + (jf << 2)) = v;
    }
  }
  __syncthreads();
  {
    ush* kp = kimg + (((size_t)blockIdx.x) << 13);   // rows 32*sub.. of 64j tile
#pragma unroll
    for (int m = 0; m < 4; ++m) {
      int idx = tid + (m << 8);
      int j = idx >> 5, st = idx & 31;
      int s = st ^ (j & 7);
      u32 hw[4];
#pragma unroll
      for (int k = 0; k < 4; ++k) {
        float a  = Xs[(8 * s + 2 * k) * 37 + j];
        float c2 = Xs[(8 * s + 2 * k + 1) * 37 + j];
        hw[k] = pk2h(a, c2);
      }
      u32x4 v; v.x = hw[0]; v.y = hw[1]; v.z = hw[2]; v.w = hw[3];
      *(u32x4*)(kp + (idx << 3)) = v;
    }
  }
  {
    const size_t tbase = ((size_t)((b << 6) + (jt >> 1))) << 14;  // 64j tile base
#pragma unroll
    for (int m = 0; m < 4; ++m) {
      int e = tid + (m << 8);
      int lqe = e & 15, ge = (e >> 4) & 3, ne = (e >> 6) & 7, qe = e >> 9;
      int c = (qe << 7) + (ne << 4) + lqe;
      const float* xr = Xs + c * 37 + (ge << 3);
      u32x4 v;
      v.x = pk2h(xr[0], xr[1]);
      v.y = pk2h(xr[2], xr[3]);
      v.z = pk2h(xr[4], xr[5]);
      v.w = pk2h(xr[6], xr[7]);
      *(u32x4*)(vimg + tbase + ((size_t)qe << 13) + (ne << 10) + (sub << 9)
                + (ge << 7) + (lqe << 3)) = v;
    }
  }
  {
    const int j = tid & 31, s = tid >> 5;
    float acc = 0.f;
#pragma unroll 8
    for (int k = 0; k < 32; ++k)
      acc += g[(s << 5) + k] * Xs[((s << 5) + k) * 37 + j];
    Ps[j * 9 + s] = acc;
  }
  __syncthreads();
  if (tid < 32) {
    float a = 0.f;
#pragma unroll
    for (int s = 0; s < 8; ++s) a += Ps[tid * 9 + s];
    r2[(b << 12) + j0 + tid] = a;
  }
}

// K3: QT=32, JT=64, 512 threads, 8 waves = (p:2 i) x (q:2 c) x (h:2 j).
// Producer/consumer (S once), 64 tiles (halved sync cost), PV via K=32 MFMA.
__launch_bounds__(512, 4)
__global__ void k_attn(const float* __restrict__ x1, const ush* __restrict__ kimg,
                       const ush* __restrict__ vimg, const float* __restrict__ M,
                       const float* __restrict__ r2, float* __restrict__ out) {
  extern __shared__ ush lds[];
  const int tid  = threadIdx.x;
  const int lane = tid & 63;
  const int w    = tid >> 6;
  const int h    = w & 1;          // j-group (32 j each)
  const int q    = (w >> 1) & 1;   // c-group (0 = producer)
  const int p    = w >> 2;         // i-group
  const int g    = lane >> 4;
  const int lq   = lane & 15;
  const int phb  = (p << 1) + h;

  int bid = (int)blockIdx.x;
  bid = (bid & 7) * 64 + (bid >> 3);        // bijective XCD swizzle (512 = 8*64)
  const int b  = bid >> 7;
  const int i0 = (bid & 127) << 5;

  const float* x1b = x1 + ((size_t)b << 20);

  // ---- Q-prep (VALU f32, two 16-i passes); x1f @0 (18KB), Qhi @ byte 18432 ----
  float* x1f = (float*)lds;                 // [256][18] f32
  ush* Qhi = lds + 9216;                    // [32][256] halves
  for (int ih = 0; ih < 2; ++ih) {
    {
      const int jf = tid & 3, c0 = tid >> 2;
#pragma unroll
      for (int m = 0; m < 2; ++m) {
        int c = c0 + (m << 7);
        float4 v = *(const float4*)(x1b + ((size_t)c << 12) + i0 + (ih << 4) + (jf << 2));
        *(float4*)(x1f + c * 18 + (jf << 2)) = v;
      }
    }
    __syncthreads();
    {
      const int tc = tid & 63, iq = tid >> 6;   // i = 16ih + 2iq + e
      float acc[4][2];
#pragma unroll
      for (int a = 0; a < 4; ++a) { acc[a][0] = 0.f; acc[a][1] = 0.f; }
#pragma unroll 4
      for (int c = 0; c < CC; ++c) {
        float4 mv = *(const float4*)(M + c * CC + (tc << 2));
        float x0  = x1f[c * 18 + (iq << 1)];
        float x1v = x1f[c * 18 + (iq << 1) + 1];
        acc[0][0] += mv.x * x0; acc[0][1] += mv.x * x1v;
        acc[1][0] += mv.y * x0; acc[1][1] += mv.y * x1v;
        acc[2][0] += mv.z * x0; acc[2][1] += mv.z * x1v;
        acc[3][0] += mv.w * x0; acc[3][1] += mv.w * x1v;
      }
#pragma unroll
      for (int e = 0; e < 2; ++e) {
        int i = (ih << 4) + (iq << 1) + e;
        u32x2 hw;
        hw.x = pk2h(acc[0][e], acc[1][e]);
        hw.y = pk2h(acc[2][e], acc[3][e]);
        *(u32x2*)(Qhi + (i << 8) + (tc << 2)) = hw;
      }
    }
    __syncthreads();
  }

  // ---- preload Q fragments (producers only) ----
  Frag8 QBh[8];
  if (q == 0) {
    const int qoff = ((p << 4) + lq) << 8;
#pragma unroll
    for (int cs = 0; cs < 8; ++cs)
      QBh[cs].u4 = *(const u32x4*)(Qhi + qoff + (cs << 5) + (g << 3));
  }
  __syncthreads();

  // ---- main flash loop: 64 tiles of 64 j ----
  f32x4 vacc[8];
#pragma unroll
  for (int n = 0; n < 8; ++n) vacc[n] = (f32x4){0.f, 0.f, 0.f, 0.f};
  float m_run = -3.0e38f, l_run = 0.f;

  const int sx   = lq & 7;
  const int koff = ((h << 5) + lq) << 8;    // K row (halves); +4096 for jj=1
  const float* r2p = r2 + (b << 12) + (h << 5) + (g << 2);
  const size_t bt = (size_t)(b << 6);       // 64 tiles/batch
  const ush* vbase = vimg + ((size_t)b << 20) + (q << 13) + (h << 9) + (g << 7) + (lq << 3);

  ush* Pbh  = lds + 32768 + phb * 640;      // [16 i][40 halves] per (p,h)
  float* Scf = (float*)(lds + 35328);       // byte 70656: [4 phb][64 lane]
  const int phb64 = phb << 6;

  Frag8 Vd[8];
  float4 r2a0, r2a1, r2b0, r2b1;

  // prologue: K(0) DMA x4, V(0) x8, r2(0) x2 (producers); wait K(0) only.
  {
    const ush* gk = kimg + (bt << 14);
    gload16(gk + ((size_t)tid << 3),          lds + (tid << 3));
    gload16(gk + ((size_t)(tid + 512) << 3),  lds + ((tid + 512) << 3));
    gload16(gk + ((size_t)(tid + 1024) << 3), lds + ((tid + 1024) << 3));
    gload16(gk + ((size_t)(tid + 1536) << 3), lds + ((tid + 1536) << 3));
    __builtin_amdgcn_sched_barrier(0);
#pragma unroll
    for (int n = 0; n < 8; ++n)
      Vd[n].u4 = *(const u32x4*)(vbase + (n << 10));
    if (q == 0) {
      r2a0 = *(const float4*)(r2p);
      r2a1 = *(const float4*)(r2p + 16);
    }
  }
  __builtin_amdgcn_sched_barrier(0);
  if (q == 0) asm volatile("s_waitcnt vmcnt(10)" ::: "memory");
  else        asm volatile("s_waitcnt vmcnt(8)" ::: "memory");
  __builtin_amdgcn_sched_barrier(0);
  __builtin_amdgcn_s_barrier();

  auto body = [&](int t, float4& r20c, float4& r21c, float4& r20n, float4& r21n) {
    const int cur = (t & 1) << 14;           // halves: buffers at 0 / 32KB
    if (t + 1 < 64) {
      const int nxt = cur ^ 16384;
      const ush* gk = kimg + ((bt + t + 1) << 14);
      gload16(gk + ((size_t)tid << 3),          lds + nxt + (tid << 3));
      gload16(gk + ((size_t)(tid + 512) << 3),  lds + nxt + ((tid + 512) << 3));
      gload16(gk + ((size_t)(tid + 1024) << 3), lds + nxt + ((tid + 1024) << 3));
      gload16(gk + ((size_t)(tid + 1536) << 3), lds + nxt + ((tid + 1536) << 3));
    }
    __builtin_amdgcn_sched_barrier(0);

    float scl;
    if (q == 0) {
      // ---- producer: S once (16 MFMA32, 4 chains), softmax, publish P+scl ----
      const ush* kb = lds + cur;
      f32x4 a00 = {0.f,0.f,0.f,0.f}, a01 = {0.f,0.f,0.f,0.f};
      f32x4 a10 = {0.f,0.f,0.f,0.f}, a11 = {0.f,0.f,0.f,0.f};
#pragma unroll
      for (int cs = 0; cs < 8; cs += 2) {
        int st1 = ((cs << 2) + g) ^ sx;
        int st2 = (((cs + 1) << 2) + g) ^ sx;
        Frag8 A0a, A1a, A0b, A1b;
        A0a.u4 = *(const u32x4*)(kb + koff + (st1 << 3));
        A1a.u4 = *(const u32x4*)(kb + koff + 4096 + (st1 << 3));
        A0b.u4 = *(const u32x4*)(kb + koff + (st2 << 3));
        A1b.u4 = *(const u32x4*)(kb + koff + 4096 + (st2 << 3));
        a00 = MFMA32(A0a.f, QBh[cs].f, a00);
        a10 = MFMA32(A1a.f, QBh[cs].f, a10);
        a01 = MFMA32(A0b.f, QBh[cs + 1].f, a01);
        a11 = MFMA32(A1b.f, QBh[cs + 1].f, a11);
      }
      if (t + 1 < 64) asm volatile("s_waitcnt vmcnt(4)" ::: "memory");
      else            asm volatile("s_waitcnt vmcnt(0)" ::: "memory");
      __builtin_amdgcn_sched_barrier(0);

      float s0 = a00[0] + a01[0] + r20c.x, s1 = a00[1] + a01[1] + r20c.y;
      float s2 = a00[2] + a01[2] + r20c.z, s3 = a00[3] + a01[3] + r20c.w;
      float s4 = a10[0] + a11[0] + r21c.x, s5 = a10[1] + a11[1] + r21c.y;
      float s6 = a10[2] + a11[2] + r21c.z, s7 = a10[3] + a11[3] + r21c.w;
      float mx = fmaxf(fmaxf(fmaxf(s0, s1), fmaxf(s2, s3)),
                       fmaxf(fmaxf(s4, s5), fmaxf(s6, s7)));
      mx = fmaxf(mx, __shfl_xor(mx, 16));
      mx = fmaxf(mx, __shfl_xor(mx, 32));
      float mn = fmaxf(m_run, mx);
      scl = __expf(m_run - mn);
      float p0 = __expf(s0 - mn), p1 = __expf(s1 - mn);
      float p2 = __expf(s2 - mn), p3 = __expf(s3 - mn);
      float p4 = __expf(s4 - mn), p5 = __expf(s5 - mn);
      float p6 = __expf(s6 - mn), p7 = __expf(s7 - mn);
      float rs = ((p0 + p1) + (p2 + p3)) + ((p4 + p5) + (p6 + p7));
      rs += __shfl_xor(rs, 16);
      rs += __shfl_xor(rs, 32);
      l_run = l_run * scl + rs;
      m_run = mn;
      u32x2 pw0; pw0.x = pkrtz(p0, p1); pw0.y = pkrtz(p2, p3);
      u32x2 pw1; pw1.x = pkrtz(p4, p5); pw1.y = pkrtz(p6, p7);
      *(u32x2*)(Pbh + lq * 40 + (g << 2))      = pw0;
      *(u32x2*)(Pbh + lq * 40 + 16 + (g << 2)) = pw1;
      Scf[phb64 + lane] = scl;
      asm volatile("s_waitcnt lgkmcnt(0)" ::: "memory");
    } else {
      if (t + 1 < 64) asm volatile("s_waitcnt vmcnt(4)" ::: "memory");
      else            asm volatile("s_waitcnt vmcnt(0)" ::: "memory");
    }
    __builtin_amdgcn_sched_barrier(0);
    __builtin_amdgcn_s_barrier();            // P + scl visible

    Frag8 Pf8;
    Pf8.u4 = *(const u32x4*)(Pbh + lq * 40 + (g << 3));
    if (q == 1) scl = Scf[phb64 + lane];

    if (!__all(scl == 1.0f)) {
#pragma unroll
      for (int n = 0; n < 8; ++n) {
        vacc[n][0] *= scl; vacc[n][1] *= scl;
        vacc[n][2] *= scl; vacc[n][3] *= scl;
      }
    }
#pragma unroll
    for (int n = 0; n < 8; ++n)
      vacc[n] = MFMA32(Vd[n].f, Pf8.f, vacc[n]);

    if (t + 1 < 64) {
      const ush* vt_ = vbase + ((size_t)(t + 1) << 14);
#pragma unroll
      for (int n = 0; n < 8; ++n)
        Vd[n].u4 = *(const u32x4*)(vt_ + (n << 10));
      if (q == 0) {
        r20n = *(const float4*)(r2p + ((t + 1) << 6));
        r21n = *(const float4*)(r2p + ((t + 1) << 6) + 16);
      }
      __builtin_amdgcn_sched_barrier(0);
      if (q == 0) asm volatile("s_waitcnt vmcnt(10)" ::: "memory");
      else        asm volatile("s_waitcnt vmcnt(8)" ::: "memory");
    }
    __builtin_amdgcn_sched_barrier(0);
    __builtin_amdgcn_s_barrier();            // K(t+1) ready, P consumed
  };

  for (int tt = 0; tt < 64; tt += 2) {
    body(tt,     r2a0, r2a1, r2b0, r2b1);
    body(tt + 1, r2b0, r2b1, r2a0, r2a1);
  }

  // ---- merge j-halves, normalize, store ----
  __syncthreads();
  float* Cmb = (float*)lds;                 // [2 p][256 c][17] f32 = 34816B
  float* Msm = (float*)(lds + 17408);       // byte 34816: [2 p][2 h][16]
  float* Lsm = Msm + 64;
  if (q == 0 && g == 0) {
    Msm[p * 32 + h * 16 + lq] = m_run;
    Lsm[p * 32 + h * 16 + lq] = l_run;
  }
  __syncthreads();
  float m_own = (q == 0) ? m_run : Msm[p * 32 + h * 16 + lq];
  float l_own = (q == 0) ? l_run : Lsm[p * 32 + h * 16 + lq];
  float mo  = Msm[p * 32 + (1 - h) * 16 + lq];
  float lo2 = Lsm[p * 32 + (1 - h) * 16 + lq];
  float mt    = fmaxf(m_own, mo);
  float aSelf = __expf(m_own - mt);
  float l_tot = l_own * aSelf + lo2 * __expf(mo - mt);

  if (h == 0) {
    float* cb_ = Cmb + p * (CC * RSC);
#pragma unroll
    for (int n = 0; n < 8; ++n)
#pragma unroll
      for (int r = 0; r < 4; ++r) {
        int c = (q << 7) + (n << 4) + (g << 2) + r;
        cb_[c * RSC + lq] = vacc[n][r] * aSelf;
      }
  }
  __syncthreads();
  if (h == 1) {
    const float* cb_ = Cmb + p * (CC * RSC);
    float inv = 1.f / l_tot;
    float* ob = out + ((size_t)b << 20) + i0 + (p << 4) + lq;
#pragma unroll
    for (int n = 0; n < 8; ++n)
#pragma unroll
      for (int r = 0; r < 4; ++r) {
        int c = (q << 7) + (n << 4) + (g << 2) + r;
        ob[(size_t)c << 12] = (vacc[n][r] * aSelf + cb_[c * RSC + lq]) * inv;
      }
  }
}

extern "C" void kernel_launch(void* const* d_in, const int* in_sizes, int n_in,
                              void* d_out, int out_size, void* d_ws, size_t ws_size,
                              hipStream_t stream) {
  const float* x1 = (const float*)d_in[0];
  const float* x2 = (const float*)d_in[1];
  const float* w1 = (const float*)d_in[2];
  const float* b1 = (const float*)d_in[3];
  const float* w2 = (const float*)d_in[4];
  // b2 (d_in[5]) contributes only row-constant energy terms -> cancels in softmax.

  float* M  = (float*)d_ws;            // 256KB
  float* g  = M + 65536;
  float* r2 = g + 256;                 // 64KB
  ush* kimg = (ush*)(r2 + 16384);      // 8MB: 64j tiles, 32KB each
  ush* vimg = kimg + 4194304;          // 8MB: 64j tiles, PV-fragment order
  float* outp = (float*)d_out;

  const int LDS_BYTES = 71680;
  (void)hipFuncSetAttribute((const void*)k_attn,
                            hipFuncAttributeMaxDynamicSharedMemorySize, LDS_BYTES);

  k_prep<<<CC, 256, 0, stream>>>(w1, w2, b1, M, g);
  k_cvt<<<BB * (NN / 32), 256, 0, stream>>>(x2, g, kimg, vimg, r2);
  k_attn<<<BB * (NN / 32), 512, LDS_BYTES, stream>>>(x1, kimg, vimg, M, r2, outp);
  (void)in_sizes; (void)n_in; (void)out_size; (void)ws_size;
}

// Round 16
// 274.543 us; speedup vs baseline: 1.5153x; 1.3478x over previous
//
#include <hip/hip_runtime.h>

typedef _Float16 f16;
typedef _Float16 f16x8 __attribute__((ext_vector_type(8)));
typedef _Float16 f16x4 __attribute__((ext_vector_type(4)));
typedef float    f32x4 __attribute__((ext_vector_type(4)));
typedef unsigned int u32;
typedef u32 u32x2 __attribute__((ext_vector_type(2)));
typedef u32 u32x4 __attribute__((ext_vector_type(4)));
typedef unsigned short ush;

#define CC 256
#define NN 4096
#define BB 4
#define RSC 17          // combine buffer stride (f32)

union Frag8 { u32x4 u4; f16x8 f; };
union Frag4 { u32x2 u2; f16x4 f; };

static __device__ __forceinline__ u32 pkrtz(float a, float b) {
  auto t = __builtin_amdgcn_cvt_pkrtz(a, b);
  return __builtin_bit_cast(u32, t);
}
static __device__ __forceinline__ ush f2h(float x) {   // RNE
  f16 h = (f16)x;
  return __builtin_bit_cast(ush, h);
}
static __device__ __forceinline__ u32 pk2h(float a, float b) {
  return (u32)f2h(a) | ((u32)f2h(b) << 16);
}

static __device__ __forceinline__ void gload16(const ush* g, ush* l) {
  __builtin_amdgcn_global_load_lds(
      (const __attribute__((address_space(1))) u32*)g,
      (__attribute__((address_space(3))) u32*)l, 16, 0, 0);
}

#define MFMA32(A, B, C) __builtin_amdgcn_mfma_f32_16x16x32_f16((A), (B), (C), 0, 0, 0)
#define MFMA16(A, B, C) __builtin_amdgcn_mfma_f32_16x16x16f16((A), (B), (C), 0, 0, 0)

// K1: M[c][cp] = sum_o w1[o,c]*w2[o,cp] ; g[cp] = sum_o b1[o]*w2[o,cp]
__global__ void k_prep(const float* __restrict__ w1, const float* __restrict__ w2,
                       const float* __restrict__ b1, float* __restrict__ M,
                       float* __restrict__ g) {
  const int c  = blockIdx.x;
  const int cp = threadIdx.x;
  float acc = 0.f;
#pragma unroll 8
  for (int o = 0; o < CC; ++o)
    acc += w1[o * CC + c] * w2[o * CC + cp];
  M[c * CC + cp] = acc;
  if (c == 0) {
    float ga = 0.f;
    for (int o = 0; o < CC; ++o)
      ga += b1[o] * w2[o * CC + cp];
    g[cp] = ga;
  }
}

// K-cvt: x2 tile -> kimg (swizzled [j][c] LDS byte-image, 16KB/32j-tile) +
// vimg (PV-fragment order) + r2[b,j] = sum_c g[c]*x2[b,c,j].  (fp16 RNE)
__global__ void k_cvt(const float* __restrict__ x2, const float* __restrict__ g,
                      ush* __restrict__ kimg, ush* __restrict__ vimg,
                      float* __restrict__ r2) {
  __shared__ float Xs[256 * 37];
  __shared__ float Ps[32 * 9];
  const int tid = threadIdx.x;
  const int b   = blockIdx.x >> 7;
  const int jt  = blockIdx.x & 127;
  const int j0  = jt << 5;
  const float* x2b = x2 + ((size_t)b << 20);
  {
    const int jf = tid & 7, c0 = tid >> 3;
#pragma unroll
    for (int m = 0; m < 8; ++m) {
      int c = c0 + (m << 5);
      float4 v = *(const float4*)(x2b + ((size_t)c << 12) + j0 + (jf << 2));
      *(float4*)(Xs + c * 37 + (jf << 2)) = v;
    }
  }
  __syncthreads();
  const size_t tile = ((size_t)blockIdx.x) << 13;   // halves
  {
    ush* kp = kimg + tile;
#pragma unroll
    for (int m = 0; m < 4; ++m) {
      int idx = tid + (m << 8);
      int j = idx >> 5, st = idx & 31;
      int s = st ^ (j & 7);
      u32 hw[4];
#pragma unroll
      for (int k = 0; k < 4; ++k) {
        float a  = Xs[(8 * s + 2 * k) * 37 + j];
        float c2 = Xs[(8 * s + 2 * k + 1) * 37 + j];
        hw[k] = pk2h(a, c2);
      }
      u32x4 v; v.x = hw[0]; v.y = hw[1]; v.z = hw[2]; v.w = hw[3];
      *(u32x4*)(kp + (idx << 3)) = v;
    }
  }
  {
    ush* vp = vimg + tile;
#pragma unroll
    for (int mm = 0; mm < 4; ++mm) {
      int e = tid + (mm << 8);
      int lqe = e & 15, ge = (e >> 4) & 3, he = (e >> 6) & 1, me = e >> 7;
      int c0 = lqe + (me << 5);
      int q0 = (he << 4) + (ge << 2);
      const float* r0 = Xs + c0 * 37 + q0;
      const float* r1 = Xs + (c0 + 16) * 37 + q0;
      u32x4 v;
      v.x = pk2h(r0[0], r0[1]);
      v.y = pk2h(r0[2], r0[3]);
      v.z = pk2h(r1[0], r1[1]);
      v.w = pk2h(r1[2], r1[3]);
      *(u32x4*)(vp + (e << 3)) = v;
    }
  }
  {
    const int j = tid & 31, s = tid >> 5;
    float acc = 0.f;
#pragma unroll 8
    for (int k = 0; k < 32; ++k)
      acc += g[(s << 5) + k] * Xs[((s << 5) + k) * 37 + j];
    Ps[j * 9 + s] = acc;
  }
  __syncthreads();
  if (tid < 32) {
    float a = 0.f;
#pragma unroll
    for (int s = 0; s < 8; ++s) a += Ps[tid * 9 + s];
    r2[(b << 12) + j0 + tid] = a;
  }
}

// K3: QT=32, 512 threads, 8 waves = (p:2 i) x (q:2 c) x (h:2 j).
// Producer/consumer (r13) + depth-2 latency cover at ZERO register cost:
// K tri-buffered LDS (K(t+3) issued at tail of t, ~2.5-tile cover),
// V/r2 issued at tail for t+1 into the SAME register set (~1-tile cover),
// ONE barrier + ONE counted vmcnt(2) per tile, P/scl parity-double-buffered.
__launch_bounds__(512, 4)
__global__ void k_attn(const float* __restrict__ x1, const ush* __restrict__ kimg,
                       const ush* __restrict__ vimg, const float* __restrict__ M,
                       const float* __restrict__ r2, float* __restrict__ out) {
  extern __shared__ ush lds[];
  const int tid  = threadIdx.x;
  const int lane = tid & 63;
  const int w    = tid >> 6;
  const int h    = w & 1;          // j-group
  const int q    = (w >> 1) & 1;   // c-group (0 = producer)
  const int p    = w >> 2;         // i-group
  const int g    = lane >> 4;
  const int lq   = lane & 15;
  const int phb  = (p << 1) + h;

  int bid = (int)blockIdx.x;
  bid = (bid & 7) * 64 + (bid >> 3);        // bijective XCD swizzle (512 = 8*64)
  const int b  = bid >> 7;
  const int i0 = (bid & 127) << 5;

  const float* x1b = x1 + ((size_t)b << 20);

  // ---- Q-prep (VALU f32, two 16-i passes); x1f @0 (18KB), Qhi @ byte 18432 ----
  float* x1f = (float*)lds;                 // [256][18] f32
  ush* Qhi = lds + 9216;                    // [32][256] halves
  for (int ih = 0; ih < 2; ++ih) {
    {
      const int jf = tid & 3, c0 = tid >> 2;
#pragma unroll
      for (int m = 0; m < 2; ++m) {
        int c = c0 + (m << 7);
        float4 v = *(const float4*)(x1b + ((size_t)c << 12) + i0 + (ih << 4) + (jf << 2));
        *(float4*)(x1f + c * 18 + (jf << 2)) = v;
      }
    }
    __syncthreads();
    {
      const int tc = tid & 63, iq = tid >> 6;   // i = 16ih + 2iq + e
      float acc[4][2];
#pragma unroll
      for (int a = 0; a < 4; ++a) { acc[a][0] = 0.f; acc[a][1] = 0.f; }
#pragma unroll 4
      for (int c = 0; c < CC; ++c) {
        float4 mv = *(const float4*)(M + c * CC + (tc << 2));
        float x0  = x1f[c * 18 + (iq << 1)];
        float x1v = x1f[c * 18 + (iq << 1) + 1];
        acc[0][0] += mv.x * x0; acc[0][1] += mv.x * x1v;
        acc[1][0] += mv.y * x0; acc[1][1] += mv.y * x1v;
        acc[2][0] += mv.z * x0; acc[2][1] += mv.z * x1v;
        acc[3][0] += mv.w * x0; acc[3][1] += mv.w * x1v;
      }
#pragma unroll
      for (int e = 0; e < 2; ++e) {
        int i = (ih << 4) + (iq << 1) + e;
        u32x2 hw;
        hw.x = pk2h(acc[0][e], acc[1][e]);
        hw.y = pk2h(acc[2][e], acc[3][e]);
        *(u32x2*)(Qhi + (i << 8) + (tc << 2)) = hw;
      }
    }
    __syncthreads();
  }

  // ---- preload Q fragments (producers only) ----
  Frag8 QBh[8];
  if (q == 0) {
    const int qoff = ((p << 4) + lq) << 8;
#pragma unroll
    for (int cs = 0; cs < 8; ++cs)
      QBh[cs].u4 = *(const u32x4*)(Qhi + qoff + (cs << 5) + (g << 3));
  }
  __syncthreads();

  // ---- main flash loop ----
  f32x4 vacc[8];
#pragma unroll
  for (int n = 0; n < 8; ++n) vacc[n] = (f32x4){0.f, 0.f, 0.f, 0.f};
  float m_run = -3.0e38f, l_run = 0.f;

  const int sx   = lq & 7;
  const int koff = ((h << 4) + lq) << 8;    // K row (halves)
  const float* r2p = r2 + (b << 12) + (h << 4) + (g << 2);
  const size_t bt = (size_t)(b << 7);
  const ush* vbase = vimg + (bt << 13) + (q << 12) + (h << 9) + (g << 7) + (lq << 3);

  // LDS: K tri-buffer halves {0, 8192, 16384}; P/scl parity-dbuf at byte 49152.
  u32x2* Pb  = (u32x2*)(lds + 24576);       // [2 par][4 phb][64 lane] x 8B
  float* Scf = (float*)(lds + 26624);       // byte 53248: [2 par][4 phb][64]

  Frag8 Vd[4];
  float4 r2c;

  // prologue: K(0..2) into buf0..2 (steady-state issue order), V(0), r2(0).
  {
    const ush* gk0 = kimg + (bt << 13);
    gload16(gk0 + ((size_t)tid << 3),         lds + (tid << 3));
    gload16(gk0 + ((size_t)(tid + 512) << 3), lds + ((tid + 512) << 3));
    const ush* gk1 = kimg + ((bt + 1) << 13);
    gload16(gk1 + ((size_t)tid << 3),         lds + 8192 + (tid << 3));
    gload16(gk1 + ((size_t)(tid + 512) << 3), lds + 8192 + ((tid + 512) << 3));
    __builtin_amdgcn_sched_barrier(0);
#pragma unroll
    for (int m = 0; m < 4; ++m)
      Vd[m].u4 = *(const u32x4*)(vbase + (m << 10));
    if (q == 0) r2c = *(const float4*)(r2p);
    __builtin_amdgcn_sched_barrier(0);
    const ush* gk2 = kimg + ((bt + 2) << 13);
    gload16(gk2 + ((size_t)tid << 3),         lds + 16384 + (tid << 3));
    gload16(gk2 + ((size_t)(tid + 512) << 3), lds + 16384 + ((tid + 512) << 3));
  }
  __builtin_amdgcn_sched_barrier(0);
  if (q == 0) asm volatile("s_waitcnt vmcnt(7)" ::: "memory");
  else        asm volatile("s_waitcnt vmcnt(6)" ::: "memory");
  __builtin_amdgcn_sched_barrier(0);
  __builtin_amdgcn_s_barrier();             // K(0) landed for all waves

  int bufRd = 0;                            // halves offset of current K buffer
  for (int t = 0; t < 128; ++t) {
    const int par = (t & 1) << 8;           // P/scl parity offset (entries)
    float scl;
    Frag4 Pf;
    if (q == 0) {
      // ---- producer: S once, softmax, publish P + scl ----
      const ush* kb = lds + bufRd;
      f32x4 a1 = {0.f,0.f,0.f,0.f}, a2 = {0.f,0.f,0.f,0.f};
#pragma unroll
      for (int cs = 0; cs < 8; cs += 2) {
        int st1 = ((cs << 2) + g) ^ sx;
        int st2 = (((cs + 1) << 2) + g) ^ sx;
        Frag8 A1; A1.u4 = *(const u32x4*)(kb + koff + (st1 << 3));
        Frag8 A2; A2.u4 = *(const u32x4*)(kb + koff + (st2 << 3));
        a1 = MFMA32(A1.f, QBh[cs].f, a1);
        a2 = MFMA32(A2.f, QBh[cs + 1].f, a2);
      }
      if (t <= 125) asm volatile("s_waitcnt vmcnt(2)" ::: "memory");
      else          asm volatile("s_waitcnt vmcnt(0)" ::: "memory");
      __builtin_amdgcn_sched_barrier(0);

      float s0 = a1[0] + a2[0] + r2c.x, s1 = a1[1] + a2[1] + r2c.y;
      float s2 = a1[2] + a2[2] + r2c.z, s3 = a1[3] + a2[3] + r2c.w;
      float mx = fmaxf(fmaxf(s0, s1), fmaxf(s2, s3));
      mx = fmaxf(mx, __shfl_xor(mx, 16));
      mx = fmaxf(mx, __shfl_xor(mx, 32));
      float mn = fmaxf(m_run, mx);
      scl = __expf(m_run - mn);
      float p0 = __expf(s0 - mn), p1 = __expf(s1 - mn);
      float p2 = __expf(s2 - mn), p3 = __expf(s3 - mn);
      float rs = p0 + p1 + p2 + p3;
      rs += __shfl_xor(rs, 16);
      rs += __shfl_xor(rs, 32);
      l_run = l_run * scl + rs;
      m_run = mn;
      Pf.u2.x = pkrtz(p0, p1);
      Pf.u2.y = pkrtz(p2, p3);
      Pb[par + (phb << 6) + lane] = Pf.u2;
      Scf[par + (phb << 6) + lane] = scl;
      asm volatile("s_waitcnt lgkmcnt(0)" ::: "memory");
    } else {
      if (t <= 125) asm volatile("s_waitcnt vmcnt(2)" ::: "memory");
      else          asm volatile("s_waitcnt vmcnt(0)" ::: "memory");
    }
    __builtin_amdgcn_sched_barrier(0);
    __builtin_amdgcn_s_barrier();           // P(t)+scl visible; K(t+1) landed

    if (q == 1) {
      Pf.u2 = Pb[par + (phb << 6) + lane];
      scl   = Scf[par + (phb << 6) + lane];
    }

    if (!__all(scl == 1.0f)) {
#pragma unroll
      for (int n = 0; n < 8; ++n) {
        vacc[n][0] *= scl; vacc[n][1] *= scl;
        vacc[n][2] *= scl; vacc[n][3] *= scl;
      }
    }
#pragma unroll
    for (int m = 0; m < 4; ++m) {
      Frag4 Va, Vb;
      Va.u2.x = Vd[m].u4.x; Va.u2.y = Vd[m].u4.y;     // n = 2m
      Vb.u2.x = Vd[m].u4.z; Vb.u2.y = Vd[m].u4.w;     // n = 2m+1
      vacc[2 * m]     = MFMA16(Va.f, Pf.f, vacc[2 * m]);
      vacc[2 * m + 1] = MFMA16(Vb.f, Pf.f, vacc[2 * m + 1]);
    }

    // ---- tail: issue V(t+1)+r2(t+1) (same regs, WAR-safe) and K(t+3) ----
    __builtin_amdgcn_sched_barrier(0);
    if (t + 1 < 128) {
      const ush* vt_ = vbase + ((size_t)(t + 1) << 13);
#pragma unroll
      for (int m = 0; m < 4; ++m)
        Vd[m].u4 = *(const u32x4*)(vt_ + (m << 10));
      if (q == 0) r2c = *(const float4*)(r2p + ((t + 1) << 5));
    }
    if (t + 3 < 128) {
      const ush* gk = kimg + ((bt + t + 3) << 13);
      gload16(gk + ((size_t)tid << 3),         lds + bufRd + (tid << 3));
      gload16(gk + ((size_t)(tid + 512) << 3), lds + bufRd + ((tid + 512) << 3));
    }
    __builtin_amdgcn_sched_barrier(0);
    bufRd = (bufRd == 16384) ? 0 : bufRd + 8192;
  }

  // ---- merge j-halves, normalize, store ----
  __syncthreads();
  float* Cmb = (float*)lds;                 // [2 p][256 c][17] f32 = 34816B
  float* Msm = (float*)(lds + 17408);       // byte 34816: [2 p][2 h][16]
  float* Lsm = Msm + 64;
  if (q == 0 && g == 0) {
    Msm[p * 32 + h * 16 + lq] = m_run;
    Lsm[p * 32 + h * 16 + lq] = l_run;
  }
  __syncthreads();
  float m_own = (q == 0) ? m_run : Msm[p * 32 + h * 16 + lq];
  float l_own = (q == 0) ? l_run : Lsm[p * 32 + h * 16 + lq];
  float mo  = Msm[p * 32 + (1 - h) * 16 + lq];
  float lo2 = Lsm[p * 32 + (1 - h) * 16 + lq];
  float mt    = fmaxf(m_own, mo);
  float aSelf = __expf(m_own - mt);
  float l_tot = l_own * aSelf + lo2 * __expf(mo - mt);

  if (h == 0) {
    float* cb_ = Cmb + p * (CC * RSC);
#pragma unroll
    for (int n = 0; n < 8; ++n)
#pragma unroll
      for (int r = 0; r < 4; ++r) {
        int c = (q << 7) + (n << 4) + (g << 2) + r;
        cb_[c * RSC + lq] = vacc[n][r] * aSelf;
      }
  }
  __syncthreads();
  if (h == 1) {
    const float* cb_ = Cmb + p * (CC * RSC);
    float inv = 1.f / l_tot;
    float* ob = out + ((size_t)b << 20) + i0 + (p << 4) + lq;
#pragma unroll
    for (int n = 0; n < 8; ++n)
#pragma unroll
      for (int r = 0; r < 4; ++r) {
        int c = (q << 7) + (n << 4) + (g << 2) + r;
        ob[(size_t)c << 12] = (vacc[n][r] * aSelf + cb_[c * RSC + lq]) * inv;
      }
  }
}

extern "C" void kernel_launch(void* const* d_in, const int* in_sizes, int n_in,
                              void* d_out, int out_size, void* d_ws, size_t ws_size,
                              hipStream_t stream) {
  const float* x1 = (const float*)d_in[0];
  const float* x2 = (const float*)d_in[1];
  const float* w1 = (const float*)d_in[2];
  const float* b1 = (const float*)d_in[3];
  const float* w2 = (const float*)d_in[4];
  // b2 (d_in[5]) contributes only row-constant energy terms -> cancels in softmax.

  float* M  = (float*)d_ws;            // 256KB
  float* g  = M + 65536;
  float* r2 = g + 256;                 // 64KB
  ush* kimg = (ush*)(r2 + 16384);      // 8MB, per-tile 16KB LDS byte-images
  ush* vimg = kimg + 4194304;          // 8MB, per-tile PV-fragment order
  float* outp = (float*)d_out;

  const int LDS_BYTES = 55296;
  (void)hipFuncSetAttribute((const void*)k_attn,
                            hipFuncAttributeMaxDynamicSharedMemorySize, LDS_BYTES);

  k_prep<<<CC, 256, 0, stream>>>(w1, w2, b1, M, g);
  k_cvt<<<BB * (NN / 32), 256, 0, stream>>>(x2, g, kimg, vimg, r2);
  k_attn<<<BB * (NN / 32), 512, LDS_BYTES, stream>>>(x1, kimg, vimg, M, r2, outp);
  (void)in_sizes; (void)n_in; (void)out_size; (void)ws_size;
}